// Round 1
// baseline (1627.051 us; speedup 1.0000x reference)
//
#include <hip/hip_runtime.h>
#include <math.h>

typedef __bf16 bf16;
typedef __bf16 bf16x4 __attribute__((ext_vector_type(4)));
typedef __bf16 bf16x8 __attribute__((ext_vector_type(8)));
typedef float floatx4 __attribute__((ext_vector_type(4)));

#define MFMA16(a, b, c) __builtin_amdgcn_mfma_f32_16x16x32_bf16((a), (b), (c), 0, 0, 0)

static constexpr int NROWS = 8192;
static constexpr int DCH = 512;

// ---------------- fp32 -> bf16 convert (float4 vectorized) ----------------
__global__ void cvt_bf16_kernel(const float* __restrict__ in, bf16* __restrict__ out, int n4) {
    int i = blockIdx.x * blockDim.x + threadIdx.x;
    if (i < n4) {
        float4 v = ((const float4*)in)[i];
        bf16x4 o;
        o[0] = (bf16)v.x; o[1] = (bf16)v.y; o[2] = (bf16)v.z; o[3] = (bf16)v.w;
        ((bf16x4*)out)[i] = o;
    }
}

// ---------------- generic projection GEMM: C = sum_chunks A_c @ W[:, woff_c:+512].T + bias ----------------
// A chunks: bf16 [8192, 512] row-major. W: bf16 [512, ldw] row-major (nn.Linear weight).
// out: bf16; trans=0 -> out[m*ldo+n], trans=1 -> out[n*ldo+m] (for V^T).
// Block 256 thr (4 waves), WG tile 128x128, wave tile 64x64 (4x4 of 16x16x32 MFMA).
__launch_bounds__(256)
__global__ void proj_gemm(const bf16* __restrict__ A0, const bf16* __restrict__ A1,
                          const bf16* __restrict__ A2, int nchunk,
                          const bf16* __restrict__ W, int ldw,
                          int woff0, int woff1, int woff2,
                          const float* __restrict__ bias,
                          bf16* __restrict__ out, int ldo, int trans) {
    const int lane = threadIdx.x & 63;
    const int wv = threadIdx.x >> 6;
    const int m0 = blockIdx.y * 128 + (wv >> 1) * 64;
    const int n0 = blockIdx.x * 128 + (wv & 1) * 64;
    const int lm = lane & 15;
    const int lk8 = (lane >> 4) * 8;
    const int r0 = (lane >> 4) * 4;

    floatx4 acc[4][4];
    #pragma unroll
    for (int mt = 0; mt < 4; ++mt)
        #pragma unroll
        for (int nt = 0; nt < 4; ++nt)
            acc[mt][nt] = (floatx4){0.f, 0.f, 0.f, 0.f};

    const bf16* As[3] = {A0, A1, A2};
    const int wofs[3] = {woff0, woff1, woff2};

    for (int c = 0; c < nchunk; ++c) {
        const bf16* __restrict__ A = As[c];
        const bf16* __restrict__ Wc = W + wofs[c];
        #pragma unroll 2
        for (int kk = 0; kk < 512; kk += 32) {
            bf16x8 a[4], b[4];
            #pragma unroll
            for (int mt = 0; mt < 4; ++mt)
                a[mt] = *(const bf16x8*)(A + (size_t)(m0 + mt * 16 + lm) * 512 + kk + lk8);
            #pragma unroll
            for (int nt = 0; nt < 4; ++nt)
                b[nt] = *(const bf16x8*)(Wc + (size_t)(n0 + nt * 16 + lm) * ldw + kk + lk8);
            #pragma unroll
            for (int mt = 0; mt < 4; ++mt)
                #pragma unroll
                for (int nt = 0; nt < 4; ++nt)
                    acc[mt][nt] = MFMA16(a[mt], b[nt], acc[mt][nt]);
        }
    }

    // epilogue: C/D layout col = lane&15, row = (lane>>4)*4 + i
    #pragma unroll
    for (int mt = 0; mt < 4; ++mt)
        #pragma unroll
        for (int nt = 0; nt < 4; ++nt)
            #pragma unroll
            for (int i = 0; i < 4; ++i) {
                int m = m0 + mt * 16 + r0 + i;
                int n = n0 + nt * 16 + lm;
                float v = acc[mt][nt][i] + bias[n];
                if (trans) out[(size_t)n * ldo + m] = (bf16)v;
                else       out[(size_t)m * ldo + n] = (bf16)v;
            }
}

// ---------------- gate: w1 = sigmoid(sigmoid(z1) - sigmoid(z2)) ----------------
__global__ void gate_kernel(const bf16* __restrict__ z1, const bf16* __restrict__ z2,
                            float* __restrict__ w1, int n) {
    int i = blockIdx.x * blockDim.x + threadIdx.x;
    if (i < n) {
        float g1 = 1.f / (1.f + __expf(-(float)z1[i]));
        float g2 = 1.f / (1.f + __expf(-(float)z2[i]));
        w1[i] = 1.f / (1.f + __expf(-(g1 - g2)));
    }
}

// ---------------- fused dual attention ----------------
// out[q,d] = w1 * (softmax(Q K1^T * s) V)[q,d] + (1-w1) * (softmax(Q K2^T * s) V)[q,d]
// Logits ~N(0,1) (max |logit| ~ 6) -> exp without max subtraction is safe in fp32.
// Block: 512 thr (8 waves). Q-tile 32 rows (resident in LDS). K-tile 64 rows/iter.
// Phase A: waves 0-3 compute S1 tiles, waves 4-7 S2 (each 16x32 strip over K=512),
//          exp -> P1/P2 bf16 in LDS, fp32 row-sums into lsum via LDS atomics.
// Phase B: wave w owns D-slice [64w, 64w+64): O += P @ Vt-slice (Vt is [512][8192]).
__launch_bounds__(512)
__global__ void attn_kernel(const bf16* __restrict__ Q, const bf16* __restrict__ K1g,
                            const bf16* __restrict__ K2g, const bf16* __restrict__ Vt,
                            const float* __restrict__ W1, float* __restrict__ out) {
    __shared__ bf16 Qs[32][520];   // +8 pad: 16B-aligned rows, 2-way-max bank aliasing
    __shared__ bf16 P1[32][72];    // +8 pad
    __shared__ bf16 P2[32][72];
    __shared__ float lsum[2][32];

    const int tid = threadIdx.x;
    const int lane = tid & 63;
    const int wv = tid >> 6;              // 0..7
    const int q0 = blockIdx.x * 32;
    const int lm = lane & 15;
    const int lk8 = (lane >> 4) * 8;
    const int r0 = (lane >> 4) * 4;

    // stage Q tile: 32 rows x 512 bf16 = 2048 chunks of 8; 512 threads x 4 chunks
    #pragma unroll
    for (int j = 0; j < 4; ++j) {
        int c = tid + 512 * j;
        int row = c >> 6;
        int col8 = (c & 63) * 8;
        bf16x8 v = *(const bf16x8*)(Q + (size_t)(q0 + row) * 512 + col8);
        *(bf16x8*)(&Qs[row][col8]) = v;
    }
    if (tid < 64) lsum[tid >> 5][tid & 31] = 0.f;
    __syncthreads();

    floatx4 O1[2][4], O2[2][4];
    #pragma unroll
    for (int m = 0; m < 2; ++m)
        #pragma unroll
        for (int nt = 0; nt < 4; ++nt) {
            O1[m][nt] = (floatx4){0.f, 0.f, 0.f, 0.f};
            O2[m][nt] = (floatx4){0.f, 0.f, 0.f, 0.f};
        }

    const int which = wv >> 2;            // 0 -> S1/K1, 1 -> S2/K2
    const int idx = wv & 3;
    const int mt = idx & 1;               // q m-tile (rows mt*16..+15)
    const int ntb = (idx >> 1) * 2;       // k n-tile base (this wave does ntb, ntb+1)
    const bf16* __restrict__ Kg = which ? K2g : K1g;
    bf16* __restrict__ Pbuf = which ? &P2[0][0] : &P1[0][0];
    const int d0 = wv * 64;
    const float scale = 0.044194173824159216f;  // 1/sqrt(512)

    for (int kt = 0; kt < NROWS; kt += 64) {
        // ---- phase A: S tiles (two 16x16 tiles per wave, K=512) ----
        floatx4 s0 = (floatx4){0.f, 0.f, 0.f, 0.f};
        floatx4 s1 = (floatx4){0.f, 0.f, 0.f, 0.f};
        #pragma unroll 4
        for (int kk = 0; kk < 512; kk += 32) {
            bf16x8 a = *(const bf16x8*)(&Qs[mt * 16 + lm][kk + lk8]);
            bf16x8 b0 = *(const bf16x8*)(Kg + (size_t)(kt + ntb * 16 + lm) * 512 + kk + lk8);
            bf16x8 b1 = *(const bf16x8*)(Kg + (size_t)(kt + ntb * 16 + 16 + lm) * 512 + kk + lk8);
            s0 = MFMA16(a, b0, s0);
            s1 = MFMA16(a, b1, s1);
        }
        float rs[4];
        #pragma unroll
        for (int i = 0; i < 4; ++i) {
            float e0 = __expf(s0[i] * scale);
            float e1 = __expf(s1[i] * scale);
            rs[i] = e0 + e1;
            Pbuf[(mt * 16 + r0 + i) * 72 + ntb * 16 + lm] = (bf16)e0;
            Pbuf[(mt * 16 + r0 + i) * 72 + ntb * 16 + 16 + lm] = (bf16)e1;
        }
        #pragma unroll
        for (int i = 0; i < 4; ++i) {
            float v = rs[i];
            v += __shfl_xor(v, 1); v += __shfl_xor(v, 2);
            v += __shfl_xor(v, 4); v += __shfl_xor(v, 8);
            if (lm == 0) atomicAdd(&lsum[which][mt * 16 + r0 + i], v);
        }
        __syncthreads();

        // ---- phase B: O += P @ Vt-slice (K=64 -> 2 MFMA k-steps) ----
        #pragma unroll
        for (int kk2 = 0; kk2 < 2; ++kk2) {
            bf16x8 p1[2], p2[2], bv[4];
            #pragma unroll
            for (int m = 0; m < 2; ++m) {
                p1[m] = *(const bf16x8*)(&P1[m * 16 + lm][kk2 * 32 + lk8]);
                p2[m] = *(const bf16x8*)(&P2[m * 16 + lm][kk2 * 32 + lk8]);
            }
            #pragma unroll
            for (int nt = 0; nt < 4; ++nt)
                bv[nt] = *(const bf16x8*)(Vt + (size_t)(d0 + nt * 16 + lm) * NROWS + kt + kk2 * 32 + lk8);
            #pragma unroll
            for (int m = 0; m < 2; ++m)
                #pragma unroll
                for (int nt = 0; nt < 4; ++nt) {
                    O1[m][nt] = MFMA16(p1[m], bv[nt], O1[m][nt]);
                    O2[m][nt] = MFMA16(p2[m], bv[nt], O2[m][nt]);
                }
        }
        __syncthreads();
    }

    // ---- epilogue: normalize + gate ----
    #pragma unroll
    for (int m = 0; m < 2; ++m)
        #pragma unroll
        for (int nt = 0; nt < 4; ++nt)
            #pragma unroll
            for (int i = 0; i < 4; ++i) {
                int q = q0 + m * 16 + r0 + i;
                int d = d0 + nt * 16 + lm;
                float l1 = lsum[0][m * 16 + r0 + i];
                float l2 = lsum[1][m * 16 + r0 + i];
                float w1 = W1[(size_t)q * 512 + d];
                out[(size_t)q * 512 + d] = w1 * (O1[m][nt][i] / l1) + (1.f - w1) * (O2[m][nt][i] / l2);
            }
}

// ---------------- host launch ----------------
extern "C" void kernel_launch(void* const* d_in, const int* in_sizes, int n_in,
                              void* d_out, int out_size, void* d_ws, size_t ws_size,
                              hipStream_t stream) {
    const float* sp   = (const float*)d_in[0];
    const float* om1  = (const float*)d_in[1];
    const float* om2  = (const float*)d_in[2];
    const float* q_w  = (const float*)d_in[3];
    const float* q_b  = (const float*)d_in[4];
    const float* k1_w = (const float*)d_in[5];
    const float* k1_b = (const float*)d_in[6];
    const float* k2_w = (const float*)d_in[7];
    const float* k2_b = (const float*)d_in[8];
    const float* v_w  = (const float*)d_in[9];
    const float* v_b  = (const float*)d_in[10];
    const float* c1_w = (const float*)d_in[11];
    const float* c1_b = (const float*)d_in[12];
    float* out = (float*)d_out;

    char* ws = (char*)d_ws;
    size_t off = 0;
    auto alloc = [&](size_t bytes) -> void* {
        void* p = ws + off;
        off += (bytes + 255) & ~(size_t)255;
        return p;
    };
    const size_t NM = (size_t)NROWS * DCH;         // 8192*512
    bf16* spb  = (bf16*)alloc(NM * 2);
    bf16* om1b = (bf16*)alloc(NM * 2);
    bf16* om2b = (bf16*)alloc(NM * 2);
    bf16* qwb  = (bf16*)alloc(512 * 512 * 2);
    bf16* k1wb = (bf16*)alloc(512 * 512 * 2);
    bf16* k2wb = (bf16*)alloc(512 * 512 * 2);
    bf16* vwb  = (bf16*)alloc(512 * 1536 * 2);
    bf16* c1wb = (bf16*)alloc(512 * 1024 * 2);
    bf16* Q    = (bf16*)alloc(NM * 2);
    bf16* K1   = (bf16*)alloc(NM * 2);
    bf16* K2   = (bf16*)alloc(NM * 2);
    bf16* Vt   = (bf16*)alloc(NM * 2);             // [512][8192]
    bf16* Z1   = (bf16*)alloc(NM * 2);
    bf16* Z2   = (bf16*)alloc(NM * 2);
    float* W1g = (float*)alloc(NM * 4);

    // converts
    auto cvt = [&](const float* src, bf16* dst, int n) {
        int n4 = n / 4;
        cvt_bf16_kernel<<<(n4 + 255) / 256, 256, 0, stream>>>(src, dst, n4);
    };
    cvt(sp,  spb,  (int)NM);
    cvt(om1, om1b, (int)NM);
    cvt(om2, om2b, (int)NM);
    cvt(q_w,  qwb,  512 * 512);
    cvt(k1_w, k1wb, 512 * 512);
    cvt(k2_w, k2wb, 512 * 512);
    cvt(v_w,  vwb,  512 * 1536);
    cvt(c1_w, c1wb, 512 * 1024);

    // projections
    dim3 pgrid(512 / 128, NROWS / 128);   // (4, 64)
    proj_gemm<<<pgrid, 256, 0, stream>>>(spb,  nullptr, nullptr, 1, qwb,  512,  0, 0, 0,    q_b,  Q,  512,  0);
    proj_gemm<<<pgrid, 256, 0, stream>>>(om1b, nullptr, nullptr, 1, k1wb, 512,  0, 0, 0,    k1_b, K1, 512,  0);
    proj_gemm<<<pgrid, 256, 0, stream>>>(om2b, nullptr, nullptr, 1, k2wb, 512,  0, 0, 0,    k2_b, K2, 512,  0);
    proj_gemm<<<pgrid, 256, 0, stream>>>(spb,  om1b, om2b,    3, vwb,  1536, 0, 512, 1024, v_b,  Vt, NROWS, 1);
    proj_gemm<<<pgrid, 256, 0, stream>>>(spb,  om1b, nullptr, 2, c1wb, 1024, 0, 512, 0,    c1_b, Z1, 512,  0);
    proj_gemm<<<pgrid, 256, 0, stream>>>(spb,  om2b, nullptr, 2, c1wb, 1024, 0, 512, 0,    c1_b, Z2, 512,  0);

    // gate
    gate_kernel<<<((int)NM + 255) / 256, 256, 0, stream>>>(Z1, Z2, W1g, (int)NM);

    // attention
    attn_kernel<<<NROWS / 32, 512, 0, stream>>>(Q, K1, K2, Vt, W1g, out);
}

// Round 2
// 1073.318 us; speedup vs baseline: 1.5159x; 1.5159x over previous
//
#include <hip/hip_runtime.h>
#include <math.h>

typedef __bf16 bf16;
typedef __bf16 bf16x4 __attribute__((ext_vector_type(4)));
typedef __bf16 bf16x8 __attribute__((ext_vector_type(8)));
typedef float floatx4 __attribute__((ext_vector_type(4)));

#define MFMA16(a, b, c) __builtin_amdgcn_mfma_f32_16x16x32_bf16((a), (b), (c), 0, 0, 0)

static constexpr int NROWS = 8192;
static constexpr int DCH = 512;
static constexpr int NSPLIT = 4;           // K-dim split for attention
static constexpr int KRANGE = NROWS / NSPLIT;   // 2048 K-rows per block
static constexpr int KTILE = 128;          // K rows per iteration

// ---------------- fp32 -> bf16 convert (float4 vectorized) ----------------
__global__ void cvt_bf16_kernel(const float* __restrict__ in, bf16* __restrict__ out, int n4) {
    int i = blockIdx.x * blockDim.x + threadIdx.x;
    if (i < n4) {
        float4 v = ((const float4*)in)[i];
        bf16x4 o;
        o[0] = (bf16)v.x; o[1] = (bf16)v.y; o[2] = (bf16)v.z; o[3] = (bf16)v.w;
        ((bf16x4*)out)[i] = o;
    }
}

// ---------------- generic projection GEMM (unchanged from R1) ----------------
__launch_bounds__(256)
__global__ void proj_gemm(const bf16* __restrict__ A0, const bf16* __restrict__ A1,
                          const bf16* __restrict__ A2, int nchunk,
                          const bf16* __restrict__ W, int ldw,
                          int woff0, int woff1, int woff2,
                          const float* __restrict__ bias,
                          bf16* __restrict__ out, int ldo, int trans) {
    const int lane = threadIdx.x & 63;
    const int wv = threadIdx.x >> 6;
    const int m0 = blockIdx.y * 128 + (wv >> 1) * 64;
    const int n0 = blockIdx.x * 128 + (wv & 1) * 64;
    const int lm = lane & 15;
    const int lk8 = (lane >> 4) * 8;
    const int r0 = (lane >> 4) * 4;

    floatx4 acc[4][4];
    #pragma unroll
    for (int mt = 0; mt < 4; ++mt)
        #pragma unroll
        for (int nt = 0; nt < 4; ++nt)
            acc[mt][nt] = (floatx4){0.f, 0.f, 0.f, 0.f};

    const bf16* As[3] = {A0, A1, A2};
    const int wofs[3] = {woff0, woff1, woff2};

    for (int c = 0; c < nchunk; ++c) {
        const bf16* __restrict__ A = As[c];
        const bf16* __restrict__ Wc = W + wofs[c];
        #pragma unroll 2
        for (int kk = 0; kk < 512; kk += 32) {
            bf16x8 a[4], b[4];
            #pragma unroll
            for (int mt = 0; mt < 4; ++mt)
                a[mt] = *(const bf16x8*)(A + (size_t)(m0 + mt * 16 + lm) * 512 + kk + lk8);
            #pragma unroll
            for (int nt = 0; nt < 4; ++nt)
                b[nt] = *(const bf16x8*)(Wc + (size_t)(n0 + nt * 16 + lm) * ldw + kk + lk8);
            #pragma unroll
            for (int mt = 0; mt < 4; ++mt)
                #pragma unroll
                for (int nt = 0; nt < 4; ++nt)
                    acc[mt][nt] = MFMA16(a[mt], b[nt], acc[mt][nt]);
        }
    }

    #pragma unroll
    for (int mt = 0; mt < 4; ++mt)
        #pragma unroll
        for (int nt = 0; nt < 4; ++nt)
            #pragma unroll
            for (int i = 0; i < 4; ++i) {
                int m = m0 + mt * 16 + r0 + i;
                int n = n0 + nt * 16 + lm;
                float v = acc[mt][nt][i] + bias[n];
                if (trans) out[(size_t)n * ldo + m] = (bf16)v;
                else       out[(size_t)m * ldo + n] = (bf16)v;
            }
}

// ---------------- gate: w1 = sigmoid(sigmoid(z1) - sigmoid(z2)) ----------------
__global__ void gate_kernel(const bf16* __restrict__ z1, const bf16* __restrict__ z2,
                            float* __restrict__ w1, int n) {
    int i = blockIdx.x * blockDim.x + threadIdx.x;
    if (i < n) {
        float g1 = 1.f / (1.f + __expf(-(float)z1[i]));
        float g2 = 1.f / (1.f + __expf(-(float)z2[i]));
        w1[i] = 1.f / (1.f + __expf(-(g1 - g2)));
    }
}

// ---------------- fused dual attention, K-split, partial outputs ----------------
// Block (qb, split): q rows [qb*32,+32), K rows [split*2048,+2048).
// 8 waves. Phase A: wave (a=wv>>2, nq=wv&3): attn a, K-cols [nq*32,+32) of the
// 128-row K-tile, wave tile m32 x n32 (2x2 of 16x16x32 MFMA) -> no K-read
// redundancy within the block. exp -> P (bf16, LDS), row-sums accumulated
// across the whole 2048-K range (no max subtraction: logits ~N(0,1)).
// Phase B: wave wv owns d-slice [wv*64,+64), both attentions share Vt frags.
// Epilogue: unnormalized partial O (bf16) + partial l per split to workspace.
__launch_bounds__(512)
__global__ void attn_kernel(const bf16* __restrict__ Q, const bf16* __restrict__ K1g,
                            const bf16* __restrict__ K2g, const bf16* __restrict__ Vt,
                            bf16* __restrict__ Opart, float* __restrict__ Lpart) {
    __shared__ bf16 Qs[32][520];    // stride 520: 260 dw = 4 mod 8 -> conflict-free b128
    __shared__ bf16 P1[32][136];    // stride 136: 68 dw = 4 mod 8
    __shared__ bf16 P2[32][136];
    __shared__ float lsum[2][32];

    const int tid = threadIdx.x;
    const int lane = tid & 63;
    const int wv = tid >> 6;
    const int q0 = blockIdx.x * 32;
    const int k0 = blockIdx.y * KRANGE;
    const int split = blockIdx.y;
    const int lm = lane & 15;
    const int lk8 = (lane >> 4) * 8;
    const int r0 = (lane >> 4) * 4;

    // stage Q tile 32x512
    #pragma unroll
    for (int j = 0; j < 4; ++j) {
        int c = tid + 512 * j;
        int row = c >> 6;
        int col8 = (c & 63) * 8;
        *(bf16x8*)(&Qs[row][col8]) = *(const bf16x8*)(Q + (size_t)(q0 + row) * 512 + col8);
    }
    if (tid < 64) lsum[tid >> 5][tid & 31] = 0.f;
    __syncthreads();

    floatx4 O1[2][4], O2[2][4];
    #pragma unroll
    for (int mt = 0; mt < 2; ++mt)
        #pragma unroll
        for (int nt = 0; nt < 4; ++nt) {
            O1[mt][nt] = (floatx4){0.f, 0.f, 0.f, 0.f};
            O2[mt][nt] = (floatx4){0.f, 0.f, 0.f, 0.f};
        }

    const int a = wv >> 2;                 // which attention
    const int nq = wv & 3;                 // k-col slice within K-tile
    const bf16* __restrict__ Kg = a ? K2g : K1g;
    bf16 (* __restrict__ Pw)[136] = a ? P2 : P1;
    const int d0 = wv * 64;
    const float scale = 0.044194173824159216f;  // 1/sqrt(512)

    for (int kt = k0; kt < k0 + KRANGE; kt += KTILE) {
        // ---- phase A: S wave-tile m32 x n32 over K=512 ----
        floatx4 s[2][2];
        #pragma unroll
        for (int mt = 0; mt < 2; ++mt)
            #pragma unroll
            for (int nt = 0; nt < 2; ++nt)
                s[mt][nt] = (floatx4){0.f, 0.f, 0.f, 0.f};

        const bf16* __restrict__ Kb = Kg + (size_t)(kt + nq * 32 + lm) * 512;
        #pragma unroll 4
        for (int kk = 0; kk < 512; kk += 32) {
            bf16x8 a0 = *(const bf16x8*)(&Qs[lm][kk + lk8]);
            bf16x8 a1 = *(const bf16x8*)(&Qs[16 + lm][kk + lk8]);
            bf16x8 b0 = *(const bf16x8*)(Kb + kk + lk8);
            bf16x8 b1 = *(const bf16x8*)(Kb + 16 * 512 + kk + lk8);
            s[0][0] = MFMA16(a0, b0, s[0][0]);
            s[0][1] = MFMA16(a0, b1, s[0][1]);
            s[1][0] = MFMA16(a1, b0, s[1][0]);
            s[1][1] = MFMA16(a1, b1, s[1][1]);
        }

        // exp -> P, row-sum -> lsum
        #pragma unroll
        for (int mt = 0; mt < 2; ++mt)
            #pragma unroll
            for (int i = 0; i < 4; ++i) {
                float e0 = __expf(s[mt][0][i] * scale);
                float e1 = __expf(s[mt][1][i] * scale);
                Pw[mt * 16 + r0 + i][nq * 32 + lm] = (bf16)e0;
                Pw[mt * 16 + r0 + i][nq * 32 + 16 + lm] = (bf16)e1;
                float v = e0 + e1;
                v += __shfl_xor(v, 1); v += __shfl_xor(v, 2);
                v += __shfl_xor(v, 4); v += __shfl_xor(v, 8);
                if (lm == 0) atomicAdd(&lsum[a][mt * 16 + r0 + i], v);
            }
        __syncthreads();

        // ---- phase B: O += P @ Vt-slice, shared Vt frags for both attn ----
        #pragma unroll
        for (int kk2 = 0; kk2 < 4; ++kk2) {
            bf16x8 p1[2], p2[2], bv[4];
            #pragma unroll
            for (int mt = 0; mt < 2; ++mt) {
                p1[mt] = *(const bf16x8*)(&P1[mt * 16 + lm][kk2 * 32 + lk8]);
                p2[mt] = *(const bf16x8*)(&P2[mt * 16 + lm][kk2 * 32 + lk8]);
            }
            #pragma unroll
            for (int nt = 0; nt < 4; ++nt)
                bv[nt] = *(const bf16x8*)(Vt + (size_t)(d0 + nt * 16 + lm) * NROWS + kt + kk2 * 32 + lk8);
            #pragma unroll
            for (int mt = 0; mt < 2; ++mt)
                #pragma unroll
                for (int nt = 0; nt < 4; ++nt) {
                    O1[mt][nt] = MFMA16(p1[mt], bv[nt], O1[mt][nt]);
                    O2[mt][nt] = MFMA16(p2[mt], bv[nt], O2[mt][nt]);
                }
        }
        __syncthreads();
    }

    // ---- epilogue: partial O (unnormalized, bf16) + partial l ----
    bf16* __restrict__ Op1 = Opart + (size_t)(2 * split + 0) * NROWS * 512;
    bf16* __restrict__ Op2 = Opart + (size_t)(2 * split + 1) * NROWS * 512;
    #pragma unroll
    for (int mt = 0; mt < 2; ++mt)
        #pragma unroll
        for (int nt = 0; nt < 4; ++nt)
            #pragma unroll
            for (int i = 0; i < 4; ++i) {
                size_t idx = (size_t)(q0 + mt * 16 + r0 + i) * 512 + d0 + nt * 16 + lm;
                Op1[idx] = (bf16)O1[mt][nt][i];
                Op2[idx] = (bf16)O2[mt][nt][i];
            }
    if (tid < 64)
        Lpart[(size_t)(2 * split + (tid >> 5)) * NROWS + q0 + (tid & 31)] = lsum[tid >> 5][tid & 31];
}

// ---------------- combine: sum splits, normalize, gate ----------------
__global__ void combine_kernel(const bf16* __restrict__ Opart, const float* __restrict__ Lpart,
                               const float* __restrict__ W1, float* __restrict__ out, int n4) {
    int i = blockIdx.x * blockDim.x + threadIdx.x;
    if (i >= n4) return;
    int q = i >> 7;   // 128 float4-groups per 512-wide row
    float l1 = 0.f, l2 = 0.f;
    #pragma unroll
    for (int s = 0; s < NSPLIT; ++s) {
        l1 += Lpart[(size_t)(2 * s + 0) * NROWS + q];
        l2 += Lpart[(size_t)(2 * s + 1) * NROWS + q];
    }
    float o1[4] = {0.f, 0.f, 0.f, 0.f}, o2[4] = {0.f, 0.f, 0.f, 0.f};
    #pragma unroll
    for (int s = 0; s < NSPLIT; ++s) {
        bf16x4 v1 = ((const bf16x4*)(Opart + (size_t)(2 * s + 0) * NROWS * 512))[i];
        bf16x4 v2 = ((const bf16x4*)(Opart + (size_t)(2 * s + 1) * NROWS * 512))[i];
        #pragma unroll
        for (int j = 0; j < 4; ++j) { o1[j] += (float)v1[j]; o2[j] += (float)v2[j]; }
    }
    float4 w = ((const float4*)W1)[i];
    float4 r;
    r.x = w.x * (o1[0] / l1) + (1.f - w.x) * (o2[0] / l2);
    r.y = w.y * (o1[1] / l1) + (1.f - w.y) * (o2[1] / l2);
    r.z = w.z * (o1[2] / l1) + (1.f - w.z) * (o2[2] / l2);
    r.w = w.w * (o1[3] / l1) + (1.f - w.w) * (o2[3] / l2);
    ((float4*)out)[i] = r;
}

// ---------------- host launch ----------------
extern "C" void kernel_launch(void* const* d_in, const int* in_sizes, int n_in,
                              void* d_out, int out_size, void* d_ws, size_t ws_size,
                              hipStream_t stream) {
    const float* sp   = (const float*)d_in[0];
    const float* om1  = (const float*)d_in[1];
    const float* om2  = (const float*)d_in[2];
    const float* q_w  = (const float*)d_in[3];
    const float* q_b  = (const float*)d_in[4];
    const float* k1_w = (const float*)d_in[5];
    const float* k1_b = (const float*)d_in[6];
    const float* k2_w = (const float*)d_in[7];
    const float* k2_b = (const float*)d_in[8];
    const float* v_w  = (const float*)d_in[9];
    const float* v_b  = (const float*)d_in[10];
    const float* c1_w = (const float*)d_in[11];
    const float* c1_b = (const float*)d_in[12];
    float* out = (float*)d_out;

    char* ws = (char*)d_ws;
    size_t off = 0;
    auto alloc = [&](size_t bytes) -> void* {
        void* p = ws + off;
        off += (bytes + 255) & ~(size_t)255;
        return p;
    };
    const size_t NM = (size_t)NROWS * DCH;

    // persistent region (live across attention)
    bf16* Q    = (bf16*)alloc(NM * 2);
    bf16* K1   = (bf16*)alloc(NM * 2);
    bf16* K2   = (bf16*)alloc(NM * 2);
    bf16* Vt   = (bf16*)alloc(NM * 2);             // [512][8192]
    float* W1g = (float*)alloc(NM * 4);

    // temp region (dead after gate) — overlaid by Opart/Lpart afterwards
    size_t mark = off;
    bf16* spb  = (bf16*)alloc(NM * 2);
    bf16* om1b = (bf16*)alloc(NM * 2);
    bf16* om2b = (bf16*)alloc(NM * 2);
    bf16* qwb  = (bf16*)alloc(512 * 512 * 2);
    bf16* k1wb = (bf16*)alloc(512 * 512 * 2);
    bf16* k2wb = (bf16*)alloc(512 * 512 * 2);
    bf16* vwb  = (bf16*)alloc(512 * 1536 * 2);
    bf16* c1wb = (bf16*)alloc(512 * 1024 * 2);
    bf16* Z1   = (bf16*)alloc(NM * 2);
    bf16* Z2   = (bf16*)alloc(NM * 2);

    // overlay: partial attention outputs (written only after gate consumed Z1/Z2)
    off = mark;
    bf16*  Opart = (bf16*)alloc((size_t)2 * NSPLIT * NM * 2);
    float* Lpart = (float*)alloc((size_t)2 * NSPLIT * NROWS * 4);

    auto cvt = [&](const float* src, bf16* dst, int n) {
        int n4 = n / 4;
        cvt_bf16_kernel<<<(n4 + 255) / 256, 256, 0, stream>>>(src, dst, n4);
    };
    cvt(sp,  spb,  (int)NM);
    cvt(om1, om1b, (int)NM);
    cvt(om2, om2b, (int)NM);
    cvt(q_w,  qwb,  512 * 512);
    cvt(k1_w, k1wb, 512 * 512);
    cvt(k2_w, k2wb, 512 * 512);
    cvt(v_w,  vwb,  512 * 1536);
    cvt(c1_w, c1wb, 512 * 1024);

    dim3 pgrid(512 / 128, NROWS / 128);
    proj_gemm<<<pgrid, 256, 0, stream>>>(spb,  nullptr, nullptr, 1, qwb,  512,  0, 0, 0,    q_b,  Q,  512,  0);
    proj_gemm<<<pgrid, 256, 0, stream>>>(om1b, nullptr, nullptr, 1, k1wb, 512,  0, 0, 0,    k1_b, K1, 512,  0);
    proj_gemm<<<pgrid, 256, 0, stream>>>(om2b, nullptr, nullptr, 1, k2wb, 512,  0, 0, 0,    k2_b, K2, 512,  0);
    proj_gemm<<<pgrid, 256, 0, stream>>>(spb,  om1b, om2b,    3, vwb,  1536, 0, 512, 1024, v_b,  Vt, NROWS, 1);
    proj_gemm<<<pgrid, 256, 0, stream>>>(spb,  om1b, nullptr, 2, c1wb, 1024, 0, 512, 0,    c1_b, Z1, 512,  0);
    proj_gemm<<<pgrid, 256, 0, stream>>>(spb,  om2b, nullptr, 2, c1wb, 1024, 0, 512, 0,    c1_b, Z2, 512,  0);

    gate_kernel<<<((int)NM + 255) / 256, 256, 0, stream>>>(Z1, Z2, W1g, (int)NM);

    dim3 agrid(NROWS / 32, NSPLIT);
    attn_kernel<<<agrid, 512, 0, stream>>>(Q, K1, K2, Vt, Opart, Lpart);

    int n4 = (int)(NM / 4);
    combine_kernel<<<(n4 + 255) / 256, 256, 0, stream>>>(Opart, Lpart, W1g, out, n4);
}

// Round 3
// 992.536 us; speedup vs baseline: 1.6393x; 1.0814x over previous
//
#include <hip/hip_runtime.h>
#include <math.h>

typedef __bf16 bf16;
typedef __bf16 bf16x4 __attribute__((ext_vector_type(4)));
typedef __bf16 bf16x8 __attribute__((ext_vector_type(8)));
typedef float floatx4 __attribute__((ext_vector_type(4)));

#define MFMA16(a, b, c) __builtin_amdgcn_mfma_f32_16x16x32_bf16((a), (b), (c), 0, 0, 0)

static constexpr int NROWS = 8192;
static constexpr int DCH = 512;
static constexpr int NSPLIT = 8;                 // K-dim split (== XCD count)
static constexpr int KRANGE = NROWS / NSPLIT;    // 1024 K-rows per block
static constexpr int KTILE = 128;                // K rows per iteration
static constexpr int NITER = KRANGE / KTILE;     // 8

// ---------------- fp32 -> bf16 convert ----------------
__global__ void cvt_bf16_kernel(const float* __restrict__ in, bf16* __restrict__ out, int n4) {
    int i = blockIdx.x * blockDim.x + threadIdx.x;
    if (i < n4) {
        float4 v = ((const float4*)in)[i];
        bf16x4 o;
        o[0] = (bf16)v.x; o[1] = (bf16)v.y; o[2] = (bf16)v.z; o[3] = (bf16)v.w;
        ((bf16x4*)out)[i] = o;
    }
}

// ---------------- merged projection GEMM: 6 projections via blockIdx.z ----------------
// z=0: Q = sp@qw'  z=1: K1 = om1@k1w'  z=2: K2 = om2@k2w'
// z=3: Vt = [sp,om1,om2]@vw' (transposed out)  z=4: Z1 = [sp,om1]@c1w'  z=5: Z2 = [sp,om2]@c1w'
__launch_bounds__(256)
__global__ void proj_gemm(const bf16* __restrict__ spb, const bf16* __restrict__ om1b,
                          const bf16* __restrict__ om2b,
                          const bf16* __restrict__ qwb, const bf16* __restrict__ k1wb,
                          const bf16* __restrict__ k2wb, const bf16* __restrict__ vwb,
                          const bf16* __restrict__ c1wb,
                          const float* __restrict__ q_b, const float* __restrict__ k1_b,
                          const float* __restrict__ k2_b, const float* __restrict__ v_b,
                          const float* __restrict__ c1_b,
                          bf16* __restrict__ Q, bf16* __restrict__ K1, bf16* __restrict__ K2,
                          bf16* __restrict__ Vt, bf16* __restrict__ Z1, bf16* __restrict__ Z2) {
    const bf16* As[3] = {nullptr, nullptr, nullptr};
    int wofs[3] = {0, 0, 0};
    int nchunk = 1, ldw = 512, ldo = 512, trans = 0;
    const bf16* W = nullptr;
    const float* bias = nullptr;
    bf16* out = nullptr;
    switch (blockIdx.z) {
        case 0: As[0] = spb;  W = qwb;  bias = q_b;  out = Q;  break;
        case 1: As[0] = om1b; W = k1wb; bias = k1_b; out = K1; break;
        case 2: As[0] = om2b; W = k2wb; bias = k2_b; out = K2; break;
        case 3: As[0] = spb; As[1] = om1b; As[2] = om2b; nchunk = 3; W = vwb; ldw = 1536;
                wofs[1] = 512; wofs[2] = 1024; bias = v_b; out = Vt; ldo = NROWS; trans = 1; break;
        case 4: As[0] = spb; As[1] = om1b; nchunk = 2; W = c1wb; ldw = 1024;
                wofs[1] = 512; bias = c1_b; out = Z1; break;
        default: As[0] = spb; As[1] = om2b; nchunk = 2; W = c1wb; ldw = 1024;
                wofs[1] = 512; bias = c1_b; out = Z2; break;
    }

    const int lane = threadIdx.x & 63;
    const int wv = threadIdx.x >> 6;
    const int m0 = blockIdx.y * 128 + (wv >> 1) * 64;
    const int n0 = blockIdx.x * 128 + (wv & 1) * 64;
    const int lm = lane & 15;
    const int lk8 = (lane >> 4) * 8;
    const int r0 = (lane >> 4) * 4;

    floatx4 acc[4][4];
    #pragma unroll
    for (int mt = 0; mt < 4; ++mt)
        #pragma unroll
        for (int nt = 0; nt < 4; ++nt)
            acc[mt][nt] = (floatx4){0.f, 0.f, 0.f, 0.f};

    for (int c = 0; c < nchunk; ++c) {
        const bf16* __restrict__ A = As[c];
        const bf16* __restrict__ Wc = W + wofs[c];
        #pragma unroll 2
        for (int kk = 0; kk < 512; kk += 32) {
            bf16x8 a[4], b[4];
            #pragma unroll
            for (int mt = 0; mt < 4; ++mt)
                a[mt] = *(const bf16x8*)(A + (size_t)(m0 + mt * 16 + lm) * 512 + kk + lk8);
            #pragma unroll
            for (int nt = 0; nt < 4; ++nt)
                b[nt] = *(const bf16x8*)(Wc + (size_t)(n0 + nt * 16 + lm) * ldw + kk + lk8);
            #pragma unroll
            for (int mt = 0; mt < 4; ++mt)
                #pragma unroll
                for (int nt = 0; nt < 4; ++nt)
                    acc[mt][nt] = MFMA16(a[mt], b[nt], acc[mt][nt]);
        }
    }

    #pragma unroll
    for (int mt = 0; mt < 4; ++mt)
        #pragma unroll
        for (int nt = 0; nt < 4; ++nt)
            #pragma unroll
            for (int i = 0; i < 4; ++i) {
                int m = m0 + mt * 16 + r0 + i;
                int n = n0 + nt * 16 + lm;
                float v = acc[mt][nt][i] + bias[n];
                if (trans) out[(size_t)n * ldo + m] = (bf16)v;
                else       out[(size_t)m * ldo + n] = (bf16)v;
            }
}

// ---------------- gate: w1 = sigmoid(sigmoid(z1) - sigmoid(z2)) ----------------
__global__ void gate_kernel(const bf16* __restrict__ z1, const bf16* __restrict__ z2,
                            float* __restrict__ w1, int n) {
    int i = blockIdx.x * blockDim.x + threadIdx.x;
    if (i < n) {
        float g1 = 1.f / (1.f + __expf(-(float)z1[i]));
        float g2 = 1.f / (1.f + __expf(-(float)z2[i]));
        w1[i] = 1.f / (1.f + __expf(-(g1 - g2)));
    }
}

// ---------------- fused dual attention, QT=64, 16 waves, dbuf P, XCD-pinned splits ----------------
// Block (qb, split): q rows [qb*64,+64), K rows [split*1024,+1024). split = blockIdx&7 -> XCD pin.
// Phase A: wave = (a=wv&1, qs=(wv>>1)&1, ns=wv>>2): S wave tile m32 (q-half) x n32 (k-slice),
//          K read direct from global (XCD-L2 hot), Q from LDS. exp -> P[a][buf] bf16.
// Phase B: wave owns d-slice [wv*32,+32) for BOTH attns (Vt read once per block).
// 1 barrier/iter via double-buffered P. Unnormalized partial O + l per split.
__launch_bounds__(1024, 4)
__global__ void attn_kernel(const bf16* __restrict__ Q, const bf16* __restrict__ K1g,
                            const bf16* __restrict__ K2g, const bf16* __restrict__ Vt,
                            bf16* __restrict__ Opart, float* __restrict__ Lpart) {
    __shared__ bf16 Qs[64][520];        // 66.5 KB; stride 130 dw -> 2-way max on b128 reads
    __shared__ bf16 P[2][2][64][136];   // [attn][buf][q][kcol], 69.6 KB
    __shared__ float lsum[2][64];

    const int tid = threadIdx.x;
    const int lane = tid & 63;
    const int wv = tid >> 6;            // 0..15
    const int bid = blockIdx.x;
    const int split = bid & 7;
    const int qb = bid >> 3;
    const int q0 = qb * 64;
    const int k0 = split * KRANGE;
    const int lm = lane & 15;
    const int lk8 = (lane >> 4) * 8;
    const int r0 = (lane >> 4) * 4;

    // stage Q tile 64x512 (1024 thr x 4 chunks of 16B)
    #pragma unroll
    for (int j = 0; j < 4; ++j) {
        int c = tid + 1024 * j;
        int row = c >> 6;
        int col8 = (c & 63) * 8;
        *(bf16x8*)(&Qs[row][col8]) = *(const bf16x8*)(Q + (size_t)(q0 + row) * 512 + col8);
    }
    if (tid < 128) lsum[tid >> 6][tid & 63] = 0.f;
    __syncthreads();

    // phase-A wave assignment
    const int pa_a = wv & 1;
    const int pa_qs = (wv >> 1) & 1;
    const int pa_ns = wv >> 2;          // 0..3
    const bf16* __restrict__ Kg = pa_a ? K2g : K1g;
    // phase-B
    const int d0 = wv * 32;

    floatx4 O1[4][2], O2[4][2];
    #pragma unroll
    for (int mt = 0; mt < 4; ++mt)
        #pragma unroll
        for (int nt = 0; nt < 2; ++nt) {
            O1[mt][nt] = (floatx4){0.f, 0.f, 0.f, 0.f};
            O2[mt][nt] = (floatx4){0.f, 0.f, 0.f, 0.f};
        }

    const float scale = 0.044194173824159216f;  // 1/sqrt(512)

    auto phaseA = [&](int kt, int buf) {
        floatx4 s[2][2];
        #pragma unroll
        for (int mt = 0; mt < 2; ++mt)
            #pragma unroll
            for (int nt = 0; nt < 2; ++nt)
                s[mt][nt] = (floatx4){0.f, 0.f, 0.f, 0.f};
        const bf16* __restrict__ Kb = Kg + (size_t)(kt + pa_ns * 32 + lm) * 512;
        #pragma unroll 4
        for (int kk = 0; kk < 512; kk += 32) {
            bf16x8 a0 = *(const bf16x8*)(&Qs[pa_qs * 32 + lm][kk + lk8]);
            bf16x8 a1 = *(const bf16x8*)(&Qs[pa_qs * 32 + 16 + lm][kk + lk8]);
            bf16x8 b0 = *(const bf16x8*)(Kb + kk + lk8);
            bf16x8 b1 = *(const bf16x8*)(Kb + 16 * 512 + kk + lk8);
            s[0][0] = MFMA16(a0, b0, s[0][0]);
            s[0][1] = MFMA16(a0, b1, s[0][1]);
            s[1][0] = MFMA16(a1, b0, s[1][0]);
            s[1][1] = MFMA16(a1, b1, s[1][1]);
        }
        #pragma unroll
        for (int mt = 0; mt < 2; ++mt)
            #pragma unroll
            for (int i = 0; i < 4; ++i) {
                float e0 = __expf(s[mt][0][i] * scale);
                float e1 = __expf(s[mt][1][i] * scale);
                int row = pa_qs * 32 + mt * 16 + r0 + i;
                P[pa_a][buf][row][pa_ns * 32 + lm] = (bf16)e0;
                P[pa_a][buf][row][pa_ns * 32 + 16 + lm] = (bf16)e1;
                float v = e0 + e1;
                v += __shfl_xor(v, 1); v += __shfl_xor(v, 2);
                v += __shfl_xor(v, 4); v += __shfl_xor(v, 8);
                if (lm == 0) atomicAdd(&lsum[pa_a][row], v);
            }
    };

    auto phaseB = [&](int kt, int buf) {
        #pragma unroll
        for (int kk2 = 0; kk2 < 4; ++kk2) {
            bf16x8 p1[4], p2[4], bv[2];
            #pragma unroll
            for (int mt = 0; mt < 4; ++mt) {
                p1[mt] = *(const bf16x8*)(&P[0][buf][mt * 16 + lm][kk2 * 32 + lk8]);
                p2[mt] = *(const bf16x8*)(&P[1][buf][mt * 16 + lm][kk2 * 32 + lk8]);
            }
            #pragma unroll
            for (int nt = 0; nt < 2; ++nt)
                bv[nt] = *(const bf16x8*)(Vt + (size_t)(d0 + nt * 16 + lm) * NROWS + kt + kk2 * 32 + lk8);
            #pragma unroll
            for (int mt = 0; mt < 4; ++mt)
                #pragma unroll
                for (int nt = 0; nt < 2; ++nt) {
                    O1[mt][nt] = MFMA16(p1[mt], bv[nt], O1[mt][nt]);
                    O2[mt][nt] = MFMA16(p2[mt], bv[nt], O2[mt][nt]);
                }
        }
    };

    phaseA(k0, 0);
    __syncthreads();
    for (int it = 0; it < NITER; ++it) {
        int cur = it & 1;
        if (it + 1 < NITER) phaseA(k0 + (it + 1) * KTILE, cur ^ 1);
        phaseB(k0 + it * KTILE, cur);
        __syncthreads();
    }

    // epilogue: partial O (unnormalized, bf16) + partial l
    bf16* __restrict__ Op1 = Opart + (size_t)(2 * split + 0) * NROWS * 512;
    bf16* __restrict__ Op2 = Opart + (size_t)(2 * split + 1) * NROWS * 512;
    #pragma unroll
    for (int mt = 0; mt < 4; ++mt)
        #pragma unroll
        for (int nt = 0; nt < 2; ++nt)
            #pragma unroll
            for (int i = 0; i < 4; ++i) {
                size_t idx = (size_t)(q0 + mt * 16 + r0 + i) * 512 + d0 + nt * 16 + lm;
                Op1[idx] = (bf16)O1[mt][nt][i];
                Op2[idx] = (bf16)O2[mt][nt][i];
            }
    if (tid < 128)
        Lpart[(size_t)(2 * split + (tid >> 6)) * NROWS + q0 + (tid & 63)] = lsum[tid >> 6][tid & 63];
}

// ---------------- combine: sum splits, normalize, gate ----------------
__global__ void combine_kernel(const bf16* __restrict__ Opart, const float* __restrict__ Lpart,
                               const float* __restrict__ W1, float* __restrict__ out, int n4) {
    int i = blockIdx.x * blockDim.x + threadIdx.x;
    if (i >= n4) return;
    int q = i >> 7;
    float l1 = 0.f, l2 = 0.f;
    #pragma unroll
    for (int s = 0; s < NSPLIT; ++s) {
        l1 += Lpart[(size_t)(2 * s + 0) * NROWS + q];
        l2 += Lpart[(size_t)(2 * s + 1) * NROWS + q];
    }
    float o1[4] = {0.f, 0.f, 0.f, 0.f}, o2[4] = {0.f, 0.f, 0.f, 0.f};
    #pragma unroll
    for (int s = 0; s < NSPLIT; ++s) {
        bf16x4 v1 = ((const bf16x4*)(Opart + (size_t)(2 * s + 0) * NROWS * 512))[i];
        bf16x4 v2 = ((const bf16x4*)(Opart + (size_t)(2 * s + 1) * NROWS * 512))[i];
        #pragma unroll
        for (int j = 0; j < 4; ++j) { o1[j] += (float)v1[j]; o2[j] += (float)v2[j]; }
    }
    float4 w = ((const float4*)W1)[i];
    float4 r;
    r.x = w.x * (o1[0] / l1) + (1.f - w.x) * (o2[0] / l2);
    r.y = w.y * (o1[1] / l1) + (1.f - w.y) * (o2[1] / l2);
    r.z = w.z * (o1[2] / l1) + (1.f - w.z) * (o2[2] / l2);
    r.w = w.w * (o1[3] / l1) + (1.f - w.w) * (o2[3] / l2);
    ((float4*)out)[i] = r;
}

// ---------------- host launch ----------------
extern "C" void kernel_launch(void* const* d_in, const int* in_sizes, int n_in,
                              void* d_out, int out_size, void* d_ws, size_t ws_size,
                              hipStream_t stream) {
    const float* sp   = (const float*)d_in[0];
    const float* om1  = (const float*)d_in[1];
    const float* om2  = (const float*)d_in[2];
    const float* q_w  = (const float*)d_in[3];
    const float* q_b  = (const float*)d_in[4];
    const float* k1_w = (const float*)d_in[5];
    const float* k1_b = (const float*)d_in[6];
    const float* k2_w = (const float*)d_in[7];
    const float* k2_b = (const float*)d_in[8];
    const float* v_w  = (const float*)d_in[9];
    const float* v_b  = (const float*)d_in[10];
    const float* c1_w = (const float*)d_in[11];
    const float* c1_b = (const float*)d_in[12];
    float* out = (float*)d_out;

    char* ws = (char*)d_ws;
    size_t off = 0;
    auto alloc = [&](size_t bytes) -> void* {
        void* p = ws + off;
        off += (bytes + 255) & ~(size_t)255;
        return p;
    };
    const size_t NM = (size_t)NROWS * DCH;

    // persistent region
    bf16* Q    = (bf16*)alloc(NM * 2);
    bf16* K1   = (bf16*)alloc(NM * 2);
    bf16* K2   = (bf16*)alloc(NM * 2);
    bf16* Vt   = (bf16*)alloc(NM * 2);             // [512][8192]
    float* W1g = (float*)alloc(NM * 4);

    // temp region (dead after gate) — overlaid by Opart/Lpart
    size_t mark = off;
    bf16* spb  = (bf16*)alloc(NM * 2);
    bf16* om1b = (bf16*)alloc(NM * 2);
    bf16* om2b = (bf16*)alloc(NM * 2);
    bf16* qwb  = (bf16*)alloc(512 * 512 * 2);
    bf16* k1wb = (bf16*)alloc(512 * 512 * 2);
    bf16* k2wb = (bf16*)alloc(512 * 512 * 2);
    bf16* vwb  = (bf16*)alloc(512 * 1536 * 2);
    bf16* c1wb = (bf16*)alloc(512 * 1024 * 2);
    bf16* Z1   = (bf16*)alloc(NM * 2);
    bf16* Z2   = (bf16*)alloc(NM * 2);

    off = mark;
    bf16*  Opart = (bf16*)alloc((size_t)2 * NSPLIT * NM * 2);     // 134 MB
    float* Lpart = (float*)alloc((size_t)2 * NSPLIT * NROWS * 4);

    auto cvt = [&](const float* src, bf16* dst, int n) {
        int n4 = n / 4;
        cvt_bf16_kernel<<<(n4 + 255) / 256, 256, 0, stream>>>(src, dst, n4);
    };
    cvt(sp,  spb,  (int)NM);
    cvt(om1, om1b, (int)NM);
    cvt(om2, om2b, (int)NM);
    cvt(q_w,  qwb,  512 * 512);
    cvt(k1_w, k1wb, 512 * 512);
    cvt(k2_w, k2wb, 512 * 512);
    cvt(v_w,  vwb,  512 * 1536);
    cvt(c1_w, c1wb, 512 * 1024);

    dim3 pgrid(512 / 128, NROWS / 128, 6);   // (4, 64, 6) = 1536 blocks, one launch
    proj_gemm<<<pgrid, 256, 0, stream>>>(spb, om1b, om2b, qwb, k1wb, k2wb, vwb, c1wb,
                                         q_b, k1_b, k2_b, v_b, c1_b,
                                         Q, K1, K2, Vt, Z1, Z2);

    gate_kernel<<<((int)NM + 255) / 256, 256, 0, stream>>>(Z1, Z2, W1g, (int)NM);

    attn_kernel<<<(NROWS / 64) * NSPLIT, 1024, 0, stream>>>(Q, K1, K2, Vt, Opart, Lpart);

    int n4 = (int)(NM / 4);
    combine_kernel<<<(n4 + 255) / 256, 256, 0, stream>>>(Opart, Lpart, W1g, out, n4);
}

// Round 4
// 727.945 us; speedup vs baseline: 2.2351x; 1.3635x over previous
//
#include <hip/hip_runtime.h>
#include <math.h>

typedef __bf16 bf16;
typedef __bf16 bf16x8 __attribute__((ext_vector_type(8)));
typedef float floatx4 __attribute__((ext_vector_type(4)));

#define MFMA16(a, b, c) __builtin_amdgcn_mfma_f32_16x16x32_bf16((a), (b), (c), 0, 0, 0)

static constexpr int NROWS = 8192;
static constexpr int DCH = 512;
static constexpr int NSPLIT = 8;                 // K-dim split (== XCD count)
static constexpr int KRANGE = NROWS / NSPLIT;    // 1024 K-rows per block
static constexpr int KTILE = 128;                // K rows per iteration
static constexpr int NITER = KRANGE / KTILE;     // 8

// Blocked layout: X_blk[r/16][c/32][16][32] bf16, each 16x32 tile = 512 elems = 1KB
// contiguous. An MFMA A/B fragment (rows r0+lm, k-cols kk..kk+32) is exactly one
// tile; lane reads 16B at tile + lm*32 + (lane>>4)*8 -> fully coalesced 1KB/wave.
// LDS copies additionally XOR-swizzle the 16B chunk index: ci' = ci ^ ((row>>1)&3)
// -> frag reads (lane row = lm) and C-layout writes are <=2-way bank aliased (free).

// ---------------- fp32 -> bf16 blocked convert ----------------
// in: [R][C] row-major fp32. out: blocked bf16. thread handles 8 consecutive cols.
__global__ void cvt_blk_kernel(const float* __restrict__ in, bf16* __restrict__ out,
                               int C, int n8) {
    int i = blockIdx.x * blockDim.x + threadIdx.x;
    if (i >= n8) return;
    int c8 = i % (C >> 3);
    int r = i / (C >> 3);
    float4 v0 = ((const float4*)in)[i * 2];
    float4 v1 = ((const float4*)in)[i * 2 + 1];
    bf16x8 o;
    o[0] = (bf16)v0.x; o[1] = (bf16)v0.y; o[2] = (bf16)v0.z; o[3] = (bf16)v0.w;
    o[4] = (bf16)v1.x; o[5] = (bf16)v1.y; o[6] = (bf16)v1.z; o[7] = (bf16)v1.w;
    int nkb = C >> 5;
    size_t e = ((size_t)(r >> 4) * nkb + (c8 >> 2)) * 512 + (r & 15) * 32 + (c8 & 3) * 8;
    *(bf16x8*)(out + e) = o;
}

// ---------------- merged projection GEMM: 6 projections via blockIdx.z ----------------
// All inputs blocked. Outputs: Q/K1/K2 blocked [8192/16][16][512], Vt blocked
// [512/16][256][512] (transposed), Z1/Z2 row-major (feed elementwise gate).
__launch_bounds__(256)
__global__ void proj_gemm(const bf16* __restrict__ spb, const bf16* __restrict__ om1b,
                          const bf16* __restrict__ om2b,
                          const bf16* __restrict__ qwb, const bf16* __restrict__ k1wb,
                          const bf16* __restrict__ k2wb, const bf16* __restrict__ vwb,
                          const bf16* __restrict__ c1wb,
                          const float* __restrict__ q_b, const float* __restrict__ k1_b,
                          const float* __restrict__ k2_b, const float* __restrict__ v_b,
                          const float* __restrict__ c1_b,
                          bf16* __restrict__ Q, bf16* __restrict__ K1, bf16* __restrict__ K2,
                          bf16* __restrict__ Vt, bf16* __restrict__ Z1, bf16* __restrict__ Z2) {
    const bf16* As[3] = {nullptr, nullptr, nullptr};
    int wofs[3] = {0, 0, 0};
    int nchunk = 1, ldw = 512, mode = 0;   // mode 0: blocked, 1: blocked-trans (Vt), 2: row-major
    const bf16* W = nullptr;
    const float* bias = nullptr;
    bf16* out = nullptr;
    switch (blockIdx.z) {
        case 0: As[0] = spb;  W = qwb;  bias = q_b;  out = Q;  break;
        case 1: As[0] = om1b; W = k1wb; bias = k1_b; out = K1; break;
        case 2: As[0] = om2b; W = k2wb; bias = k2_b; out = K2; break;
        case 3: As[0] = spb; As[1] = om1b; As[2] = om2b; nchunk = 3; W = vwb; ldw = 1536;
                wofs[1] = 512; wofs[2] = 1024; bias = v_b; out = Vt; mode = 1; break;
        case 4: As[0] = spb; As[1] = om1b; nchunk = 2; W = c1wb; ldw = 1024;
                wofs[1] = 512; bias = c1_b; out = Z1; mode = 2; break;
        default: As[0] = spb; As[1] = om2b; nchunk = 2; W = c1wb; ldw = 1024;
                wofs[1] = 512; bias = c1_b; out = Z2; mode = 2; break;
    }

    const int lane = threadIdx.x & 63;
    const int wv = threadIdx.x >> 6;
    const int m0 = blockIdx.y * 128 + (wv >> 1) * 64;
    const int n0 = blockIdx.x * 128 + (wv & 1) * 64;
    const int lm = lane & 15;
    const int lk8 = (lane >> 4) * 8;
    const int r0 = (lane >> 4) * 4;
    const int nkbW = ldw >> 5;

    floatx4 acc[4][4];
    #pragma unroll
    for (int mt = 0; mt < 4; ++mt)
        #pragma unroll
        for (int nt = 0; nt < 4; ++nt)
            acc[mt][nt] = (floatx4){0.f, 0.f, 0.f, 0.f};

    for (int c = 0; c < nchunk; ++c) {
        const bf16* __restrict__ A = As[c];
        const int wo = wofs[c];
        #pragma unroll 2
        for (int kk = 0; kk < 512; kk += 32) {
            bf16x8 a[4], b[4];
            #pragma unroll
            for (int mt = 0; mt < 4; ++mt)
                a[mt] = *(const bf16x8*)(A + ((size_t)((m0 + mt * 16) >> 4) * 16 + (kk >> 5)) * 512
                                           + lm * 32 + lk8);
            #pragma unroll
            for (int nt = 0; nt < 4; ++nt)
                b[nt] = *(const bf16x8*)(W + ((size_t)((n0 + nt * 16) >> 4) * nkbW + ((wo + kk) >> 5)) * 512
                                           + lm * 32 + lk8);
            #pragma unroll
            for (int mt = 0; mt < 4; ++mt)
                #pragma unroll
                for (int nt = 0; nt < 4; ++nt)
                    acc[mt][nt] = MFMA16(a[mt], b[nt], acc[mt][nt]);
        }
    }

    #pragma unroll
    for (int mt = 0; mt < 4; ++mt)
        #pragma unroll
        for (int nt = 0; nt < 4; ++nt)
            #pragma unroll
            for (int i = 0; i < 4; ++i) {
                int m = m0 + mt * 16 + r0 + i;
                int n = n0 + nt * 16 + lm;
                float v = acc[mt][nt][i] + bias[n];
                if (mode == 0)
                    out[((size_t)(m >> 4) * 16 + (n >> 5)) * 512 + (m & 15) * 32 + (n & 31)] = (bf16)v;
                else if (mode == 1)
                    out[((size_t)(n >> 4) * 256 + (m >> 5)) * 512 + (n & 15) * 32 + (m & 31)] = (bf16)v;
                else
                    out[(size_t)m * 512 + n] = (bf16)v;
            }
}

// ---------------- gate: w1 = sigmoid(sigmoid(z1) - sigmoid(z2)) ----------------
__global__ void gate_kernel(const bf16* __restrict__ z1, const bf16* __restrict__ z2,
                            float* __restrict__ w1, int n) {
    int i = blockIdx.x * blockDim.x + threadIdx.x;
    if (i < n) {
        float g1 = 1.f / (1.f + __expf(-(float)z1[i]));
        float g2 = 1.f / (1.f + __expf(-(float)z2[i]));
        w1[i] = 1.f / (1.f + __expf(-(g1 - g2)));
    }
}

// ---------------- fused dual attention, blocked operands, QT=32, 2 blocks/CU ----------------
// Block (qb, split=bid&7 -> XCD pinned): q rows [qb*32,+32), K rows [split*1024,+1024).
// 8 waves, 512 thr. Phase A: wave (a=wv&1, ns=wv>>1): S[32q x 32k] at k-cols kt+ns*32,
// K frags coalesced from global blocked, Q frags from swizzled LDS. exp -> P (blocked+
// swizzled LDS, dbuf). Phase B: wave owns d-slice [wv*64,+64) for both attns.
// LDS = 32K (Qs) + 32K (P) + lsum ~= 64.3 KB -> 2 blocks/CU.
__launch_bounds__(512, 4)
__global__ void attn_kernel(const bf16* __restrict__ Q, const bf16* __restrict__ K1g,
                            const bf16* __restrict__ K2g, const bf16* __restrict__ Vt,
                            bf16* __restrict__ Opart, float* __restrict__ Lpart) {
    __shared__ bf16 Qs[2 * 16 * 512];        // [2 sr][16 kb][512], swizzled chunks
    __shared__ bf16 P[2 * 2 * 8 * 512];      // [attn][buf][mt*4+kb][512], swizzled
    __shared__ float lsum[2][32];

    const int tid = threadIdx.x;
    const int lane = tid & 63;
    const int wv = tid >> 6;                 // 0..7
    const int bid = blockIdx.x;
    const int split = bid & 7;
    const int qb = bid >> 3;
    const int q0 = qb * 32;
    const int k0 = split * KRANGE;
    const int lm = lane & 15;
    const int lk8 = (lane >> 4) * 8;         // global frag chunk offset (no swizzle)
    const int r0 = (lane >> 4) * 4;
    const int ciq8 = (((lane >> 4) ^ ((lm >> 1) & 3))) * 8;  // LDS frag chunk (swizzled)

    // stage Q tile: 2 super-rows = 32KB contiguous in blocked layout, swizzle into LDS
    {
        const bf16* Qg = Q + (size_t)(q0 >> 4) * (16 * 512);
        #pragma unroll
        for (int j = 0; j < 4; ++j) {
            int ch = tid + 512 * j;          // 16B chunk index, 0..2047
            bf16x8 v = *(const bf16x8*)(Qg + ch * 8);
            int r = (ch >> 2) & 15;
            int ci = ch & 3;
            int dst = (ch & ~3) * 8 + (ci ^ ((r >> 1) & 3)) * 8;
            *(bf16x8*)(Qs + dst) = v;
        }
    }
    if (tid < 64) lsum[tid >> 5][tid & 31] = 0.f;
    __syncthreads();

    const int pa_a = wv & 1;                 // attention index for phase A
    const int pa_ns = wv >> 1;               // k-col slice (0..3) within K-tile
    const bf16* __restrict__ Kg = pa_a ? K2g : K1g;
    const int d0 = wv * 64;                  // phase-B d-slice

    floatx4 O[2][2][4];                      // [attn][mt][nt]
    #pragma unroll
    for (int a2 = 0; a2 < 2; ++a2)
        #pragma unroll
        for (int mt = 0; mt < 2; ++mt)
            #pragma unroll
            for (int nt = 0; nt < 4; ++nt)
                O[a2][mt][nt] = (floatx4){0.f, 0.f, 0.f, 0.f};

    const float scale = 0.044194173824159216f;  // 1/sqrt(512)

    auto phaseA = [&](int kt, int buf) {
        floatx4 s[2][2];
        #pragma unroll
        for (int mt = 0; mt < 2; ++mt)
            #pragma unroll
            for (int nt = 0; nt < 2; ++nt)
                s[mt][nt] = (floatx4){0.f, 0.f, 0.f, 0.f};
        // K super-rows (kt>>4)+ns*2, +1; each kb step is one 1KB tile
        const bf16* Kp0 = Kg + (size_t)((kt >> 4) + pa_ns * 2) * (16 * 512) + lm * 32 + lk8;
        const bf16* Kp1 = Kp0 + 16 * 512;
        #pragma unroll 4
        for (int kb = 0; kb < 16; ++kb) {
            bf16x8 a0 = *(const bf16x8*)(Qs + kb * 512 + lm * 32 + ciq8);
            bf16x8 a1 = *(const bf16x8*)(Qs + (16 + kb) * 512 + lm * 32 + ciq8);
            bf16x8 b0 = *(const bf16x8*)(Kp0 + kb * 512);
            bf16x8 b1 = *(const bf16x8*)(Kp1 + kb * 512);
            s[0][0] = MFMA16(a0, b0, s[0][0]);
            s[0][1] = MFMA16(a0, b1, s[0][1]);
            s[1][0] = MFMA16(a1, b0, s[1][0]);
            s[1][1] = MFMA16(a1, b1, s[1][1]);
        }
        bf16* Pb = P + ((pa_a * 2 + buf) * 8 + pa_ns) * 512;   // tile (mt=0, kb=ns); mt=1 at +4*512
        #pragma unroll
        for (int mt = 0; mt < 2; ++mt)
            #pragma unroll
            for (int i = 0; i < 4; ++i) {
                float e0 = __expf(s[mt][0][i] * scale);
                float e1 = __expf(s[mt][1][i] * scale);
                int row = r0 + i;
                int sw = (row >> 1) & 3;
                bf16* pt = Pb + mt * (4 * 512) + row * 32 + (lm & 7);
                pt[((lm >> 3) ^ sw) * 8] = (bf16)e0;
                pt[(((lm >> 3) + 2) ^ sw) * 8] = (bf16)e1;
                float v = e0 + e1;
                v += __shfl_xor(v, 1); v += __shfl_xor(v, 2);
                v += __shfl_xor(v, 4); v += __shfl_xor(v, 8);
                if (lm == 0) atomicAdd(&lsum[pa_a][mt * 16 + row], v);
            }
    };

    auto phaseB = [&](int kt, int buf) {
        #pragma unroll
        for (int kk2 = 0; kk2 < 4; ++kk2) {
            bf16x8 p[2][2], bv[4];
            #pragma unroll
            for (int a2 = 0; a2 < 2; ++a2)
                #pragma unroll
                for (int mt = 0; mt < 2; ++mt)
                    p[a2][mt] = *(const bf16x8*)(P + (((a2 * 2 + buf) * 8) + mt * 4 + kk2) * 512
                                                   + lm * 32 + ciq8);
            #pragma unroll
            for (int nt = 0; nt < 4; ++nt)
                bv[nt] = *(const bf16x8*)(Vt + ((size_t)((d0 >> 4) + nt) * 256 + (kt >> 5) + kk2) * 512
                                            + lm * 32 + lk8);
            #pragma unroll
            for (int a2 = 0; a2 < 2; ++a2)
                #pragma unroll
                for (int mt = 0; mt < 2; ++mt)
                    #pragma unroll
                    for (int nt = 0; nt < 4; ++nt)
                        O[a2][mt][nt] = MFMA16(p[a2][mt], bv[nt], O[a2][mt][nt]);
        }
    };

    phaseA(k0, 0);
    __syncthreads();
    for (int it = 0; it < NITER; ++it) {
        int cur = it & 1;
        if (it + 1 < NITER) phaseA(k0 + (it + 1) * KTILE, cur ^ 1);
        phaseB(k0 + it * KTILE, cur);
        __syncthreads();
    }

    // epilogue: unnormalized partial O (bf16, row-major) + partial l
    #pragma unroll
    for (int a2 = 0; a2 < 2; ++a2) {
        bf16* __restrict__ Op = Opart + (size_t)(2 * split + a2) * NROWS * 512;
        #pragma unroll
        for (int mt = 0; mt < 2; ++mt)
            #pragma unroll
            for (int nt = 0; nt < 4; ++nt)
                #pragma unroll
                for (int i = 0; i < 4; ++i) {
                    size_t idx = (size_t)(q0 + mt * 16 + r0 + i) * 512 + d0 + nt * 16 + lm;
                    Op[idx] = (bf16)O[a2][mt][nt][i];
                }
    }
    if (tid < 64)
        Lpart[(size_t)(2 * split + (tid >> 5)) * NROWS + q0 + (tid & 31)] = lsum[tid >> 5][tid & 31];
}

// ---------------- combine: sum splits, normalize, gate ----------------
__global__ void combine_kernel(const bf16* __restrict__ Opart, const float* __restrict__ Lpart,
                               const float* __restrict__ W1, float* __restrict__ out, int n4) {
    typedef __bf16 bf16x4v __attribute__((ext_vector_type(4)));
    int i = blockIdx.x * blockDim.x + threadIdx.x;
    if (i >= n4) return;
    int q = i >> 7;
    float l1 = 0.f, l2 = 0.f;
    #pragma unroll
    for (int s = 0; s < NSPLIT; ++s) {
        l1 += Lpart[(size_t)(2 * s + 0) * NROWS + q];
        l2 += Lpart[(size_t)(2 * s + 1) * NROWS + q];
    }
    float o1[4] = {0.f, 0.f, 0.f, 0.f}, o2[4] = {0.f, 0.f, 0.f, 0.f};
    #pragma unroll
    for (int s = 0; s < NSPLIT; ++s) {
        bf16x4v v1 = ((const bf16x4v*)(Opart + (size_t)(2 * s + 0) * NROWS * 512))[i];
        bf16x4v v2 = ((const bf16x4v*)(Opart + (size_t)(2 * s + 1) * NROWS * 512))[i];
        #pragma unroll
        for (int j = 0; j < 4; ++j) { o1[j] += (float)v1[j]; o2[j] += (float)v2[j]; }
    }
    float4 w = ((const float4*)W1)[i];
    float4 r;
    r.x = w.x * (o1[0] / l1) + (1.f - w.x) * (o2[0] / l2);
    r.y = w.y * (o1[1] / l1) + (1.f - w.y) * (o2[1] / l2);
    r.z = w.z * (o1[2] / l1) + (1.f - w.z) * (o2[2] / l2);
    r.w = w.w * (o1[3] / l1) + (1.f - w.w) * (o2[3] / l2);
    ((float4*)out)[i] = r;
}

// ---------------- host launch ----------------
extern "C" void kernel_launch(void* const* d_in, const int* in_sizes, int n_in,
                              void* d_out, int out_size, void* d_ws, size_t ws_size,
                              hipStream_t stream) {
    const float* sp   = (const float*)d_in[0];
    const float* om1  = (const float*)d_in[1];
    const float* om2  = (const float*)d_in[2];
    const float* q_w  = (const float*)d_in[3];
    const float* q_b  = (const float*)d_in[4];
    const float* k1_w = (const float*)d_in[5];
    const float* k1_b = (const float*)d_in[6];
    const float* k2_w = (const float*)d_in[7];
    const float* k2_b = (const float*)d_in[8];
    const float* v_w  = (const float*)d_in[9];
    const float* v_b  = (const float*)d_in[10];
    const float* c1_w = (const float*)d_in[11];
    const float* c1_b = (const float*)d_in[12];
    float* out = (float*)d_out;

    char* ws = (char*)d_ws;
    size_t off = 0;
    auto alloc = [&](size_t bytes) -> void* {
        void* p = ws + off;
        off += (bytes + 255) & ~(size_t)255;
        return p;
    };
    const size_t NM = (size_t)NROWS * DCH;

    // persistent region (blocked layouts)
    bf16* Q    = (bf16*)alloc(NM * 2);
    bf16* K1   = (bf16*)alloc(NM * 2);
    bf16* K2   = (bf16*)alloc(NM * 2);
    bf16* Vt   = (bf16*)alloc(NM * 2);
    float* W1g = (float*)alloc(NM * 4);

    // temp region (dead after gate) — overlaid by Opart/Lpart
    size_t mark = off;
    bf16* spb  = (bf16*)alloc(NM * 2);
    bf16* om1b = (bf16*)alloc(NM * 2);
    bf16* om2b = (bf16*)alloc(NM * 2);
    bf16* qwb  = (bf16*)alloc(512 * 512 * 2);
    bf16* k1wb = (bf16*)alloc(512 * 512 * 2);
    bf16* k2wb = (bf16*)alloc(512 * 512 * 2);
    bf16* vwb  = (bf16*)alloc(512 * 1536 * 2);
    bf16* c1wb = (bf16*)alloc(512 * 1024 * 2);
    bf16* Z1   = (bf16*)alloc(NM * 2);
    bf16* Z2   = (bf16*)alloc(NM * 2);

    off = mark;
    bf16*  Opart = (bf16*)alloc((size_t)2 * NSPLIT * NM * 2);
    float* Lpart = (float*)alloc((size_t)2 * NSPLIT * NROWS * 4);

    auto cvt = [&](const float* src, bf16* dst, int R, int C) {
        int n8 = R * C / 8;
        cvt_blk_kernel<<<(n8 + 255) / 256, 256, 0, stream>>>(src, dst, C, n8);
    };
    cvt(sp,  spb,  NROWS, 512);
    cvt(om1, om1b, NROWS, 512);
    cvt(om2, om2b, NROWS, 512);
    cvt(q_w,  qwb,  512, 512);
    cvt(k1_w, k1wb, 512, 512);
    cvt(k2_w, k2wb, 512, 512);
    cvt(v_w,  vwb,  512, 1536);
    cvt(c1_w, c1wb, 512, 1024);

    dim3 pgrid(512 / 128, NROWS / 128, 6);
    proj_gemm<<<pgrid, 256, 0, stream>>>(spb, om1b, om2b, qwb, k1wb, k2wb, vwb, c1wb,
                                         q_b, k1_b, k2_b, v_b, c1_b,
                                         Q, K1, K2, Vt, Z1, Z2);

    gate_kernel<<<((int)NM + 255) / 256, 256, 0, stream>>>(Z1, Z2, W1g, (int)NM);

    attn_kernel<<<(NROWS / 32) * NSPLIT, 512, 0, stream>>>(Q, K1, K2, Vt, Opart, Lpart);

    int n4 = (int)(NM / 4);
    combine_kernel<<<(n4 + 255) / 256, 256, 0, stream>>>(Opart, Lpart, W1g, out, n4);
}

// Round 5
// 711.274 us; speedup vs baseline: 2.2875x; 1.0234x over previous
//
#include <hip/hip_runtime.h>
#include <math.h>

typedef __bf16 bf16;
typedef __bf16 bf16x8 __attribute__((ext_vector_type(8)));
typedef float floatx4 __attribute__((ext_vector_type(4)));

#define MFMA16(a, b, c) __builtin_amdgcn_mfma_f32_16x16x32_bf16((a), (b), (c), 0, 0, 0)

static constexpr int NROWS = 8192;
static constexpr int DCH = 512;
static constexpr int NSPLIT = 8;                 // K-dim split (== XCD count)
static constexpr int KRANGE = NROWS / NSPLIT;    // 1024 K-rows per block
static constexpr int KTILE = 64;                 // K rows per iteration
static constexpr int NITER = KRANGE / KTILE;     // 16
// 1/sqrt(512) * log2(e): folded into Q so phase A is exp2f(s) directly
static constexpr float PRESCALE = 0.0637587130f;

// Blocked layout: X_blk[r/16][c/32][16][32] bf16 — 16x32 tile = 1KB contiguous;
// MFMA frag load = lane 16B at tile + lm*32 + (lane>>4)*8, fully coalesced.

// ---------------- fp32 -> bf16 blocked convert (optional scale) ----------------
__global__ void cvt_blk_kernel(const float* __restrict__ in, bf16* __restrict__ out,
                               int C, int n8, float scale) {
    int i = blockIdx.x * blockDim.x + threadIdx.x;
    if (i >= n8) return;
    int c8 = i % (C >> 3);
    int r = i / (C >> 3);
    float4 v0 = ((const float4*)in)[i * 2];
    float4 v1 = ((const float4*)in)[i * 2 + 1];
    bf16x8 o;
    o[0] = (bf16)(v0.x * scale); o[1] = (bf16)(v0.y * scale);
    o[2] = (bf16)(v0.z * scale); o[3] = (bf16)(v0.w * scale);
    o[4] = (bf16)(v1.x * scale); o[5] = (bf16)(v1.y * scale);
    o[6] = (bf16)(v1.z * scale); o[7] = (bf16)(v1.w * scale);
    int nkb = C >> 5;
    size_t e = ((size_t)(r >> 4) * nkb + (c8 >> 2)) * 512 + (r & 15) * 32 + (c8 & 3) * 8;
    *(bf16x8*)(out + e) = o;
}

// ---------------- merged projection GEMM: 6 projections via blockIdx.z ----------------
__launch_bounds__(256)
__global__ void proj_gemm(const bf16* __restrict__ spb, const bf16* __restrict__ om1b,
                          const bf16* __restrict__ om2b,
                          const bf16* __restrict__ qwb, const bf16* __restrict__ k1wb,
                          const bf16* __restrict__ k2wb, const bf16* __restrict__ vwb,
                          const bf16* __restrict__ c1wb,
                          const float* __restrict__ q_b, const float* __restrict__ k1_b,
                          const float* __restrict__ k2_b, const float* __restrict__ v_b,
                          const float* __restrict__ c1_b,
                          bf16* __restrict__ Q, bf16* __restrict__ K1, bf16* __restrict__ K2,
                          bf16* __restrict__ Vt, bf16* __restrict__ Z1, bf16* __restrict__ Z2) {
    const bf16* As[3] = {nullptr, nullptr, nullptr};
    int wofs[3] = {0, 0, 0};
    int nchunk = 1, ldw = 512, mode = 0;   // 0: blocked, 1: blocked-trans (Vt), 2: row-major
    float bscale = 1.f;
    const bf16* W = nullptr;
    const float* bias = nullptr;
    bf16* out = nullptr;
    switch (blockIdx.z) {
        case 0: As[0] = spb;  W = qwb;  bias = q_b;  out = Q;  bscale = PRESCALE; break;
        case 1: As[0] = om1b; W = k1wb; bias = k1_b; out = K1; break;
        case 2: As[0] = om2b; W = k2wb; bias = k2_b; out = K2; break;
        case 3: As[0] = spb; As[1] = om1b; As[2] = om2b; nchunk = 3; W = vwb; ldw = 1536;
                wofs[1] = 512; wofs[2] = 1024; bias = v_b; out = Vt; mode = 1; break;
        case 4: As[0] = spb; As[1] = om1b; nchunk = 2; W = c1wb; ldw = 1024;
                wofs[1] = 512; bias = c1_b; out = Z1; mode = 2; break;
        default: As[0] = spb; As[1] = om2b; nchunk = 2; W = c1wb; ldw = 1024;
                wofs[1] = 512; bias = c1_b; out = Z2; mode = 2; break;
    }

    const int lane = threadIdx.x & 63;
    const int wv = threadIdx.x >> 6;
    const int m0 = blockIdx.y * 128 + (wv >> 1) * 64;
    const int n0 = blockIdx.x * 128 + (wv & 1) * 64;
    const int lm = lane & 15;
    const int lk8 = (lane >> 4) * 8;
    const int r0 = (lane >> 4) * 4;
    const int nkbW = ldw >> 5;

    floatx4 acc[4][4];
    #pragma unroll
    for (int mt = 0; mt < 4; ++mt)
        #pragma unroll
        for (int nt = 0; nt < 4; ++nt)
            acc[mt][nt] = (floatx4){0.f, 0.f, 0.f, 0.f};

    for (int c = 0; c < nchunk; ++c) {
        const bf16* __restrict__ A = As[c];
        const int wo = wofs[c];
        #pragma unroll 2
        for (int kk = 0; kk < 512; kk += 32) {
            bf16x8 a[4], b[4];
            #pragma unroll
            for (int mt = 0; mt < 4; ++mt)
                a[mt] = *(const bf16x8*)(A + ((size_t)((m0 + mt * 16) >> 4) * 16 + (kk >> 5)) * 512
                                           + lm * 32 + lk8);
            #pragma unroll
            for (int nt = 0; nt < 4; ++nt)
                b[nt] = *(const bf16x8*)(W + ((size_t)((n0 + nt * 16) >> 4) * nkbW + ((wo + kk) >> 5)) * 512
                                           + lm * 32 + lk8);
            #pragma unroll
            for (int mt = 0; mt < 4; ++mt)
                #pragma unroll
                for (int nt = 0; nt < 4; ++nt)
                    acc[mt][nt] = MFMA16(a[mt], b[nt], acc[mt][nt]);
        }
    }

    #pragma unroll
    for (int mt = 0; mt < 4; ++mt)
        #pragma unroll
        for (int nt = 0; nt < 4; ++nt)
            #pragma unroll
            for (int i = 0; i < 4; ++i) {
                int m = m0 + mt * 16 + r0 + i;
                int n = n0 + nt * 16 + lm;
                float v = acc[mt][nt][i] + bias[n] * bscale;
                if (mode == 0)
                    out[((size_t)(m >> 4) * 16 + (n >> 5)) * 512 + (m & 15) * 32 + (n & 31)] = (bf16)v;
                else if (mode == 1)
                    out[((size_t)(n >> 4) * 256 + (m >> 5)) * 512 + (n & 15) * 32 + (m & 31)] = (bf16)v;
                else
                    out[(size_t)m * 512 + n] = (bf16)v;
            }
}

// ---------------- gate: w1 = sigmoid(sigmoid(z1) - sigmoid(z2)) ----------------
__global__ void gate_kernel(const bf16* __restrict__ z1, const bf16* __restrict__ z2,
                            float* __restrict__ w1, int n) {
    int i = blockIdx.x * blockDim.x + threadIdx.x;
    if (i < n) {
        float g1 = 1.f / (1.f + __expf(-(float)z1[i]));
        float g2 = 1.f / (1.f + __expf(-(float)z2[i]));
        w1[i] = 1.f / (1.f + __expf(-(g1 - g2)));
    }
}

// ---------------- fused dual attention ----------------
// Block (qb, split=bid&7, XCD-pinned): q rows [qb*32,+32), K rows [split*1024,+1024).
// 8 waves. Phase A: wave (a=wv&1, ns=wv>>1): S[32q x 16k] at K-rows [kt+ns*16,+16),
// K coalesced from global blocked, Q (pre-scaled by 1/sqrt(512)*log2e) from swizzled
// LDS; split accumulators (4 MFMA chains). exp2 -> P (8KB, dbuf), per-lane lsum in regs.
// Phase B: wave owns d-slice [wv*64,+64) for both attns. 1 barrier/iter.
// Epilogue: per-lane lsum reduce (one-time), O staged via LDS for full-line stores.
__launch_bounds__(512, 4)
__global__ void attn_kernel(const bf16* __restrict__ Q, const bf16* __restrict__ K1g,
                            const bf16* __restrict__ K2g, const bf16* __restrict__ Vt,
                            bf16* __restrict__ Opart, float* __restrict__ Lpart) {
    __shared__ bf16 Qs[2 * 16 * 512];        // 32 KB; reused as epilogue staging
    __shared__ bf16 P[2 * 2 * 2 * 2 * 512];  // [buf][attn][mt][kb2][16][32] = 16 KB
    __shared__ float lsum[2][32];

    const int tid = threadIdx.x;
    const int lane = tid & 63;
    const int wv = tid >> 6;                 // 0..7
    const int bid = blockIdx.x;
    const int split = bid & 7;
    const int qb = bid >> 3;
    const int q0 = qb * 32;
    const int k0 = split * KRANGE;
    const int lm = lane & 15;
    const int lk8 = (lane >> 4) * 8;
    const int r0 = (lane >> 4) * 4;
    const int ciq8 = ((lane >> 4) ^ ((lm >> 1) & 3)) * 8;  // swizzled LDS frag chunk

    // stage Q tile (2 blocked super-rows = 32 KB contiguous), swizzle into LDS
    {
        const bf16* Qg = Q + (size_t)(q0 >> 4) * (16 * 512);
        #pragma unroll
        for (int j = 0; j < 4; ++j) {
            int ch = tid + 512 * j;
            bf16x8 v = *(const bf16x8*)(Qg + ch * 8);
            int r = (ch >> 2) & 15;
            int ci = ch & 3;
            int dst = (ch & ~3) * 8 + (ci ^ ((r >> 1) & 3)) * 8;
            *(bf16x8*)(Qs + dst) = v;
        }
    }
    if (tid < 64) lsum[tid >> 5][tid & 31] = 0.f;
    __syncthreads();

    const int pa_a = wv & 1;                 // attention index for phase A
    const int pa_ns = wv >> 1;               // 16-row K slice (0..3) within 64-row tile
    const bf16* __restrict__ Kg = pa_a ? K2g : K1g;
    const int d0 = wv * 64;                  // phase-B d-slice

    floatx4 O[2][2][4];                      // [attn][mt][nt]
    #pragma unroll
    for (int a2 = 0; a2 < 2; ++a2)
        #pragma unroll
        for (int mt = 0; mt < 2; ++mt)
            #pragma unroll
            for (int nt = 0; nt < 4; ++nt)
                O[a2][mt][nt] = (floatx4){0.f, 0.f, 0.f, 0.f};

    float lrs[2][4] = {{0.f, 0.f, 0.f, 0.f}, {0.f, 0.f, 0.f, 0.f}};

    auto phaseA = [&](int kt, int buf) {
        floatx4 sE[2], sO[2];
        #pragma unroll
        for (int mt = 0; mt < 2; ++mt) {
            sE[mt] = (floatx4){0.f, 0.f, 0.f, 0.f};
            sO[mt] = (floatx4){0.f, 0.f, 0.f, 0.f};
        }
        const bf16* Kp = Kg + ((size_t)((kt >> 4) + pa_ns) * 16) * 512 + lm * 32 + lk8;
        #pragma unroll
        for (int kb = 0; kb < 16; kb += 2) {
            bf16x8 b0 = *(const bf16x8*)(Kp + kb * 512);
            bf16x8 b1 = *(const bf16x8*)(Kp + (kb + 1) * 512);
            bf16x8 a00 = *(const bf16x8*)(Qs + kb * 512 + lm * 32 + ciq8);
            bf16x8 a10 = *(const bf16x8*)(Qs + (16 + kb) * 512 + lm * 32 + ciq8);
            bf16x8 a01 = *(const bf16x8*)(Qs + (kb + 1) * 512 + lm * 32 + ciq8);
            bf16x8 a11 = *(const bf16x8*)(Qs + (17 + kb) * 512 + lm * 32 + ciq8);
            sE[0] = MFMA16(a00, b0, sE[0]);
            sE[1] = MFMA16(a10, b0, sE[1]);
            sO[0] = MFMA16(a01, b1, sO[0]);
            sO[1] = MFMA16(a11, b1, sO[1]);
        }
        const int kb2 = pa_ns >> 1;
        const int cb = (pa_ns & 1) * 2;      // 16B-chunk base within 32-col tile
        #pragma unroll
        for (int mt = 0; mt < 2; ++mt) {
            floatx4 s = sE[mt] + sO[mt];
            bf16* pt = P + ((((buf * 2 + pa_a) * 2 + mt) * 2 + kb2) * 512);
            #pragma unroll
            for (int i = 0; i < 4; ++i) {
                float e = exp2f(s[i]);       // Q pre-scaled: exp(logit/sqrt(512))
                int r = r0 + i;
                int ci = (cb + (lm >> 3)) ^ ((r >> 1) & 3);
                pt[r * 32 + ci * 8 + (lm & 7)] = (bf16)e;
                lrs[mt][i] += e;
            }
        }
    };

    auto phaseB = [&](int kt, int buf) {
        #pragma unroll
        for (int kk2 = 0; kk2 < 2; ++kk2) {
            bf16x8 p[2][2], bv[4];
            #pragma unroll
            for (int a2 = 0; a2 < 2; ++a2)
                #pragma unroll
                for (int mt = 0; mt < 2; ++mt)
                    p[a2][mt] = *(const bf16x8*)(P + (((buf * 2 + a2) * 2 + mt) * 2 + kk2) * 512
                                                   + lm * 32 + ciq8);
            #pragma unroll
            for (int nt = 0; nt < 4; ++nt)
                bv[nt] = *(const bf16x8*)(Vt + ((size_t)((d0 >> 4) + nt) * 256 + (kt >> 5) + kk2) * 512
                                            + lm * 32 + lk8);
            #pragma unroll
            for (int a2 = 0; a2 < 2; ++a2)
                #pragma unroll
                for (int mt = 0; mt < 2; ++mt)
                    #pragma unroll
                    for (int nt = 0; nt < 4; ++nt)
                        O[a2][mt][nt] = MFMA16(p[a2][mt], bv[nt], O[a2][mt][nt]);
        }
    };

    phaseA(k0, 0);
    __syncthreads();
    for (int it = 0; it < NITER; ++it) {
        int cur = it & 1;
        if (it + 1 < NITER) phaseA(k0 + (it + 1) * KTILE, cur ^ 1);
        phaseB(k0 + it * KTILE, cur);
        __syncthreads();
    }

    // one-time lsum reduction: over 16 lm-lanes (shuffle) then 4 ns-waves (LDS atomic)
    #pragma unroll
    for (int mt = 0; mt < 2; ++mt)
        #pragma unroll
        for (int i = 0; i < 4; ++i) {
            float v = lrs[mt][i];
            v += __shfl_xor(v, 1); v += __shfl_xor(v, 2);
            v += __shfl_xor(v, 4); v += __shfl_xor(v, 8);
            if (lm == 0) atomicAdd(&lsum[pa_a][mt * 16 + r0 + i], v);
        }

    // epilogue: stage O (unnormalized bf16 partials) via LDS for full-line stores
    #pragma unroll
    for (int a2 = 0; a2 < 2; ++a2) {
        __syncthreads();
        #pragma unroll
        for (int mt = 0; mt < 2; ++mt)
            #pragma unroll
            for (int nt = 0; nt < 4; ++nt)
                #pragma unroll
                for (int i = 0; i < 4; ++i) {
                    int r = mt * 16 + r0 + i;
                    int c = d0 + nt * 16 + lm;
                    int c8s = ((c >> 3) ^ ((r >> 2) & 3)) * 8;  // chunk swizzle vs quad rows
                    Qs[r * 512 + c8s + (c & 7)] = (bf16)O[a2][mt][nt][i];
                }
        __syncthreads();
        bf16* Op = Opart + (size_t)(2 * split + a2) * NROWS * 512 + (size_t)q0 * 512;
        #pragma unroll
        for (int j = 0; j < 4; ++j) {
            int ch = tid + 512 * j;
            int r = ch >> 6;
            int c8 = ch & 63;
            *(bf16x8*)(Op + ch * 8) = *(const bf16x8*)(Qs + r * 512 + ((c8 ^ ((r >> 2) & 3)) * 8));
        }
    }
    if (tid < 64)
        Lpart[(size_t)(2 * split + (tid >> 5)) * NROWS + q0 + (tid & 31)] = lsum[tid >> 5][tid & 31];
}

// ---------------- combine: sum splits, normalize, gate ----------------
__global__ void combine_kernel(const bf16* __restrict__ Opart, const float* __restrict__ Lpart,
                               const float* __restrict__ W1, float* __restrict__ out, int n4) {
    typedef __bf16 bf16x4v __attribute__((ext_vector_type(4)));
    int i = blockIdx.x * blockDim.x + threadIdx.x;
    if (i >= n4) return;
    int q = i >> 7;
    float l1 = 0.f, l2 = 0.f;
    #pragma unroll
    for (int s = 0; s < NSPLIT; ++s) {
        l1 += Lpart[(size_t)(2 * s + 0) * NROWS + q];
        l2 += Lpart[(size_t)(2 * s + 1) * NROWS + q];
    }
    float o1[4] = {0.f, 0.f, 0.f, 0.f}, o2[4] = {0.f, 0.f, 0.f, 0.f};
    #pragma unroll
    for (int s = 0; s < NSPLIT; ++s) {
        bf16x4v v1 = ((const bf16x4v*)(Opart + (size_t)(2 * s + 0) * NROWS * 512))[i];
        bf16x4v v2 = ((const bf16x4v*)(Opart + (size_t)(2 * s + 1) * NROWS * 512))[i];
        #pragma unroll
        for (int j = 0; j < 4; ++j) { o1[j] += (float)v1[j]; o2[j] += (float)v2[j]; }
    }
    float4 w = ((const float4*)W1)[i];
    float4 r;
    r.x = w.x * (o1[0] / l1) + (1.f - w.x) * (o2[0] / l2);
    r.y = w.y * (o1[1] / l1) + (1.f - w.y) * (o2[1] / l2);
    r.z = w.z * (o1[2] / l1) + (1.f - w.z) * (o2[2] / l2);
    r.w = w.w * (o1[3] / l1) + (1.f - w.w) * (o2[3] / l2);
    ((float4*)out)[i] = r;
}

// ---------------- host launch ----------------
extern "C" void kernel_launch(void* const* d_in, const int* in_sizes, int n_in,
                              void* d_out, int out_size, void* d_ws, size_t ws_size,
                              hipStream_t stream) {
    const float* sp   = (const float*)d_in[0];
    const float* om1  = (const float*)d_in[1];
    const float* om2  = (const float*)d_in[2];
    const float* q_w  = (const float*)d_in[3];
    const float* q_b  = (const float*)d_in[4];
    const float* k1_w = (const float*)d_in[5];
    const float* k1_b = (const float*)d_in[6];
    const float* k2_w = (const float*)d_in[7];
    const float* k2_b = (const float*)d_in[8];
    const float* v_w  = (const float*)d_in[9];
    const float* v_b  = (const float*)d_in[10];
    const float* c1_w = (const float*)d_in[11];
    const float* c1_b = (const float*)d_in[12];
    float* out = (float*)d_out;

    char* ws = (char*)d_ws;
    size_t off = 0;
    auto alloc = [&](size_t bytes) -> void* {
        void* p = ws + off;
        off += (bytes + 255) & ~(size_t)255;
        return p;
    };
    const size_t NM = (size_t)NROWS * DCH;

    // persistent region (blocked layouts)
    bf16* Q    = (bf16*)alloc(NM * 2);
    bf16* K1   = (bf16*)alloc(NM * 2);
    bf16* K2   = (bf16*)alloc(NM * 2);
    bf16* Vt   = (bf16*)alloc(NM * 2);
    float* W1g = (float*)alloc(NM * 4);

    // temp region (dead after gate) — overlaid by Opart/Lpart
    size_t mark = off;
    bf16* spb  = (bf16*)alloc(NM * 2);
    bf16* om1b = (bf16*)alloc(NM * 2);
    bf16* om2b = (bf16*)alloc(NM * 2);
    bf16* qwb  = (bf16*)alloc(512 * 512 * 2);
    bf16* k1wb = (bf16*)alloc(512 * 512 * 2);
    bf16* k2wb = (bf16*)alloc(512 * 512 * 2);
    bf16* vwb  = (bf16*)alloc(512 * 1536 * 2);
    bf16* c1wb = (bf16*)alloc(512 * 1024 * 2);
    bf16* Z1   = (bf16*)alloc(NM * 2);
    bf16* Z2   = (bf16*)alloc(NM * 2);

    off = mark;
    bf16*  Opart = (bf16*)alloc((size_t)2 * NSPLIT * NM * 2);
    float* Lpart = (float*)alloc((size_t)2 * NSPLIT * NROWS * 4);

    auto cvt = [&](const float* src, bf16* dst, int R, int C, float scale) {
        int n8 = R * C / 8;
        cvt_blk_kernel<<<(n8 + 255) / 256, 256, 0, stream>>>(src, dst, C, n8, scale);
    };
    cvt(sp,  spb,  NROWS, 512, 1.f);
    cvt(om1, om1b, NROWS, 512, 1.f);
    cvt(om2, om2b, NROWS, 512, 1.f);
    cvt(q_w,  qwb,  512, 512, PRESCALE);   // fold softmax scale * log2e into Q
    cvt(k1_w, k1wb, 512, 512, 1.f);
    cvt(k2_w, k2wb, 512, 512, 1.f);
    cvt(v_w,  vwb,  512, 1536, 1.f);
    cvt(c1_w, c1wb, 512, 1024, 1.f);

    dim3 pgrid(512 / 128, NROWS / 128, 6);
    proj_gemm<<<pgrid, 256, 0, stream>>>(spb, om1b, om2b, qwb, k1wb, k2wb, vwb, c1wb,
                                         q_b, k1_b, k2_b, v_b, c1_b,
                                         Q, K1, K2, Vt, Z1, Z2);

    gate_kernel<<<((int)NM + 255) / 256, 256, 0, stream>>>(Z1, Z2, W1g, (int)NM);

    attn_kernel<<<(NROWS / 32) * NSPLIT, 512, 0, stream>>>(Q, K1, K2, Vt, Opart, Lpart);

    int n4 = (int)(NM / 4);
    combine_kernel<<<(n4 + 255) / 256, 256, 0, stream>>>(Opart, Lpart, W1g, out, n4);
}